// Round 11
// baseline (407.922 us; speedup 1.0000x reference)
//
#include <hip/hip_runtime.h>
#include <hip/hip_bf16.h>

// Problem constants
#define BB 4
#define SS 2048
#define DD 1024
#define HH 16
#define DKK 64

typedef __attribute__((ext_vector_type(8))) short short8;
typedef __attribute__((ext_vector_type(4))) float f32x4;

typedef const __attribute__((address_space(1))) void gvoid;
typedef __attribute__((address_space(3))) void lvoid;

__device__ __forceinline__ unsigned short f2bf(float f) {
  unsigned int u = __builtin_bit_cast(unsigned int, f);
  u = (u + 0x7FFFu + ((u >> 16) & 1u)) >> 16;
  return (unsigned short)u;
}

__device__ __forceinline__ unsigned short f2bf_hw(float f) {
  return __builtin_bit_cast(unsigned short, __float2bfloat16(f));
}

// ---------------------------------------------------------------- converts
__global__ __launch_bounds__(256) void convert_f32_bf16(
    const float* __restrict__ in, unsigned short* __restrict__ out, int n4) {
  int i = blockIdx.x * blockDim.x + threadIdx.x;
  if (i >= n4) return;
  float4 v = reinterpret_cast<const float4*>(in)[i];
  ushort4 o;
  o.x = f2bf(v.x); o.y = f2bf(v.y); o.z = f2bf(v.z); o.w = f2bf(v.w);
  reinterpret_cast<ushort4*>(out)[i] = o;
}

// 4 weight matrices -> contiguous bf16 [wq|wk|wv|wo]
__global__ __launch_bounds__(256) void convert_w4(
    const float* __restrict__ a, const float* __restrict__ b,
    const float* __restrict__ c, const float* __restrict__ d,
    unsigned short* __restrict__ out, int n4) {
  int m = blockIdx.y;
  const float* src = (m == 0) ? a : (m == 1) ? b : (m == 2) ? c : d;
  int i = blockIdx.x * blockDim.x + threadIdx.x;
  if (i >= n4) return;
  float4 v = reinterpret_cast<const float4*>(src)[i];
  ushort4 o;
  o.x = f2bf(v.x); o.y = f2bf(v.y); o.z = f2bf(v.z); o.w = f2bf(v.w);
  reinterpret_cast<ushort4*>(out)[(size_t)m * n4 + i] = o;
}

// ---------------------------------------------------------------- merged QKV GEMM
__global__ __launch_bounds__(256) void gemm_qkv(
    const unsigned short* __restrict__ A,
    const unsigned short* __restrict__ Bm,
    unsigned short* __restrict__ Qo,
    unsigned short* __restrict__ Ko,
    unsigned short* __restrict__ Vo)
{
  __shared__ unsigned short As[128 * 32];
  __shared__ unsigned short Bs[128 * 32];
  const int K = DD;
  int bid = blockIdx.x;
  int m0 = (bid / 24) << 7;
  int n0 = (bid % 24) << 7;
  int t = threadIdx.x;
  int lane = t & 63, w = t >> 6;
  int l16 = lane & 15, lhi = lane >> 4;
  int wm = (w >> 1) * 64, wn = (w & 1) * 64;

  f32x4 acc[4][4];
#pragma unroll
  for (int i = 0; i < 4; ++i)
#pragma unroll
    for (int j = 0; j < 4; ++j) acc[i][j] = (f32x4){0.f, 0.f, 0.f, 0.f};

  for (int kt = 0; kt < K; kt += 32) {
    __syncthreads();
#pragma unroll
    for (int is = 0; is < 2; ++is) {
      int c = is * 256 + t;
      __builtin_amdgcn_global_load_lds(
          (gvoid*)(A + (size_t)(m0 + (c >> 2)) * K + kt + ((c & 3) << 3)),
          (lvoid*)(As + (size_t)(is * 256 + w * 64) * 8), 16, 0, 0);
      __builtin_amdgcn_global_load_lds(
          (gvoid*)(Bm + (size_t)(n0 + (c >> 2)) * K + kt + ((c & 3) << 3)),
          (lvoid*)(Bs + (size_t)(is * 256 + w * 64) * 8), 16, 0, 0);
    }
    __syncthreads();
    short8 af[4], bfr[4];
#pragma unroll
    for (int mf = 0; mf < 4; ++mf)
      af[mf] = *(const short8*)(As + (wm + mf * 16 + l16) * 32 + lhi * 8);
#pragma unroll
    for (int nf = 0; nf < 4; ++nf)
      bfr[nf] = *(const short8*)(Bs + (wn + nf * 16 + l16) * 32 + lhi * 8);
#pragma unroll
    for (int mf = 0; mf < 4; ++mf)
#pragma unroll
      for (int nf = 0; nf < 4; ++nf)
        acc[mf][nf] = __builtin_amdgcn_mfma_f32_16x16x32_bf16(
            af[mf], bfr[nf], acc[mf][nf], 0, 0, 0);
  }

  int mat = n0 >> 10;        // 0=Q 1=K 2=V (tile never straddles: 1024%128==0)
  int nb = n0 & 1023;
  const float qscale = 0.18033688011112042f;  // 0.125 * log2(e)
#pragma unroll
  for (int mf = 0; mf < 4; ++mf)
#pragma unroll
    for (int nf = 0; nf < 4; ++nf)
#pragma unroll
      for (int i = 0; i < 4; ++i) {
        int r = m0 + wm + mf * 16 + lhi * 4 + i;
        int c1 = nb + wn + nf * 16 + l16;
        int b = r >> 11, s = r & 2047;
        int h = c1 >> 6, dk = c1 & 63;
        if (mat == 0)
          Qo[((size_t)((b * HH + h) * SS + s) << 6) + dk] =
              f2bf(acc[mf][nf][i] * qscale);
        else if (mat == 1)
          Ko[((size_t)((b * HH + h) * SS + s) << 6) + dk] = f2bf(acc[mf][nf][i]);
        else
          Vo[(size_t)((b * HH + h) * DKK + dk) * SS + s] = f2bf(acc[mf][nf][i]);
      }
}

// ---------------------------------------------------------------- WO GEMM (fp32 out)
__global__ __launch_bounds__(256) void gemm_wo(
    const unsigned short* __restrict__ A,
    const unsigned short* __restrict__ Bm,
    float* __restrict__ C, int N, int K)
{
  __shared__ unsigned short As[128 * 32];
  __shared__ unsigned short Bs[128 * 32];
  int bid = blockIdx.x;
  int ntn = N >> 7;
  int m0 = (bid / ntn) << 7;
  int n0 = (bid % ntn) << 7;
  int t = threadIdx.x;
  int lane = t & 63, w = t >> 6;
  int l16 = lane & 15, lhi = lane >> 4;
  int wm = (w >> 1) * 64, wn = (w & 1) * 64;

  f32x4 acc[4][4];
#pragma unroll
  for (int i = 0; i < 4; ++i)
#pragma unroll
    for (int j = 0; j < 4; ++j) acc[i][j] = (f32x4){0.f, 0.f, 0.f, 0.f};

  for (int kt = 0; kt < K; kt += 32) {
    __syncthreads();
#pragma unroll
    for (int is = 0; is < 2; ++is) {
      int c = is * 256 + t;
      __builtin_amdgcn_global_load_lds(
          (gvoid*)(A + (size_t)(m0 + (c >> 2)) * K + kt + ((c & 3) << 3)),
          (lvoid*)(As + (size_t)(is * 256 + w * 64) * 8), 16, 0, 0);
      __builtin_amdgcn_global_load_lds(
          (gvoid*)(Bm + (size_t)(n0 + (c >> 2)) * K + kt + ((c & 3) << 3)),
          (lvoid*)(Bs + (size_t)(is * 256 + w * 64) * 8), 16, 0, 0);
    }
    __syncthreads();
    short8 af[4], bfr[4];
#pragma unroll
    for (int mf = 0; mf < 4; ++mf)
      af[mf] = *(const short8*)(As + (wm + mf * 16 + l16) * 32 + lhi * 8);
#pragma unroll
    for (int nf = 0; nf < 4; ++nf)
      bfr[nf] = *(const short8*)(Bs + (wn + nf * 16 + l16) * 32 + lhi * 8);
#pragma unroll
    for (int mf = 0; mf < 4; ++mf)
#pragma unroll
      for (int nf = 0; nf < 4; ++nf)
        acc[mf][nf] = __builtin_amdgcn_mfma_f32_16x16x32_bf16(
            af[mf], bfr[nf], acc[mf][nf], 0, 0, 0);
  }

#pragma unroll
  for (int mf = 0; mf < 4; ++mf)
#pragma unroll
    for (int nf = 0; nf < 4; ++nf)
#pragma unroll
      for (int i = 0; i < 4; ++i) {
        int r = m0 + wm + mf * 16 + lhi * 4 + i;
        int cc = n0 + wn + nf * 16 + l16;
        C[(size_t)r * N + cc] = acc[mf][nf][i];
      }
}

// ---------------------------------------------------------------- flash attention
// Work-balanced pairing: each wave owns TWO 16-row q-strips of the same head:
// strip s (light, ntA = s/4+1 KV tiles) and strip 127-s (heavy, ntB = 32-s/4).
// One KV stream of ntB tiles serves both fragments (shared loads for t<ntA);
// every wave does exactly ntA+ntB = 33 fragment-tile computes -> flat
// occupancy, uniform drain. Per-wave register profile identical to the
// round-6 kernel (2 x 16-row fragments). K direct from global [s][dk],
// V direct pre-transposed [dk][s]; no barriers. Fixed-offset exp2 softmax
// (partials independent), denominator via ones-column MFMA.
__global__ __launch_bounds__(256, 2) void attn_kernel(
    const unsigned short* __restrict__ Qh,
    const unsigned short* __restrict__ Kh,
    const unsigned short* __restrict__ Vt,
    unsigned short* __restrict__ O)  // bf16 [B*S, D]
{
  __shared__ unsigned short Plds[4][32 * 72];  // per-wave [2x16 rows][64 keys], pad 72

  int bid = blockIdx.x;
  int bh = bid & 63;            // b*H + h
  int sg = bid >> 6;            // strip-group 0..15
  int t = threadIdx.x, lane = t & 63, w = t >> 6;
  int l16 = lane & 15, lhi = lane >> 4;
  int s = sg * 4 + w;           // 0..63
  int rowA = s << 4;            // light strip rows [rowA, rowA+16)
  int rowB = (127 - s) << 4;    // heavy strip rows
  int ntA = (s >> 2) + 1;       // causal 64-key tiles for strip A
  int ntB = ((127 - s) >> 2) + 1;

  const unsigned short* Qb = Qh + (size_t)bh * SS * DKK;
  const unsigned short* Kb = Kh + (size_t)bh * SS * DKK;
  const unsigned short* Vb = Vt + (size_t)bh * SS * DKK;  // [dk][s]
  int b = bh >> 4, h = bh & 15;

  // Q fragments (scores pre-scaled by 0.125*log2e in the QKV GEMM)
  short8 aqA[2], aqB[2];
#pragma unroll
  for (int kc = 0; kc < 2; ++kc) {
    aqA[kc] = *(const short8*)(Qb + (size_t)(rowA + l16) * DKK + kc * 32 + lhi * 8);
    aqB[kc] = *(const short8*)(Qb + (size_t)(rowB + l16) * DKK + kc * 32 + lhi * 8);
  }

  f32x4 oaccA[4], oaccB[4], acc1A, acc1B;
  acc1A = (f32x4){0.f, 0.f, 0.f, 0.f};
  acc1B = (f32x4){0.f, 0.f, 0.f, 0.f};
#pragma unroll
  for (int d = 0; d < 4; ++d) {
    oaccA[d] = (f32x4){0.f, 0.f, 0.f, 0.f};
    oaccB[d] = (f32x4){0.f, 0.f, 0.f, 0.f};
  }

  // ones-column B fragment: column n==0 is 1.0 -> row sums via MFMA
  short8 ones;
  {
    short ov = (l16 == 0) ? (short)0x3F80 : (short)0;
#pragma unroll
    for (int j = 0; j < 8; ++j) ones[j] = ov;
  }

  short8 bk[4][2], bv[4][2];
#pragma unroll
  for (int sf = 0; sf < 4; ++sf)
#pragma unroll
    for (int kc = 0; kc < 2; ++kc)
      bk[sf][kc] = *(const short8*)(Kb + (size_t)(sf * 16 + l16) * DKK +
                                    kc * 32 + lhi * 8);
#pragma unroll
  for (int d = 0; d < 4; ++d)
#pragma unroll
    for (int kc = 0; kc < 2; ++kc)
      bv[d][kc] = *(const short8*)(Vb + (size_t)(d * 16 + l16) * SS +
                                   kc * 32 + lhi * 8);

  for (int tt = 0; tt < ntB; ++tt) {
    int kv0 = tt << 6;
    bool actA = (tt < ntA);
    // ---- S = Q K^T over 64 keys (both fragments; A only while active)
    f32x4 saccB[4], saccA[4];
#pragma unroll
    for (int sf = 0; sf < 4; ++sf) {
      saccB[sf] = (f32x4){0.f, 0.f, 0.f, 0.f};
      saccB[sf] = __builtin_amdgcn_mfma_f32_16x16x32_bf16(
          aqB[0], bk[sf][0], saccB[sf], 0, 0, 0);
      saccB[sf] = __builtin_amdgcn_mfma_f32_16x16x32_bf16(
          aqB[1], bk[sf][1], saccB[sf], 0, 0, 0);
    }
    if (actA) {
#pragma unroll
      for (int sf = 0; sf < 4; ++sf) {
        saccA[sf] = (f32x4){0.f, 0.f, 0.f, 0.f};
        saccA[sf] = __builtin_amdgcn_mfma_f32_16x16x32_bf16(
            aqA[0], bk[sf][0], saccA[sf], 0, 0, 0);
        saccA[sf] = __builtin_amdgcn_mfma_f32_16x16x32_bf16(
            aqA[1], bk[sf][1], saccA[sf], 0, 0, 0);
      }
    }
    // prefetch next K tile
    if (tt + 1 < ntB) {
      int nk = kv0 + 64;
#pragma unroll
      for (int sf = 0; sf < 4; ++sf)
#pragma unroll
        for (int kc = 0; kc < 2; ++kc)
          bk[sf][kc] = *(const short8*)(Kb + (size_t)(nk + sf * 16 + l16) * DKK +
                                        kc * 32 + lhi * 8);
    }
    // ---- P = 2^(s - 16); causal mask only on each fragment's last tile
    bool maskB = (tt == ntB - 1);
#pragma unroll
    for (int sf = 0; sf < 4; ++sf)
#pragma unroll
      for (int i = 0; i < 4; ++i) {
        float p = exp2f(saccB[sf][i] - 16.0f);
        if (maskB) {
          int key = kv0 + sf * 16 + l16;
          int qr = rowB + lhi * 4 + i;
          if (key > qr) p = 0.f;
        }
        Plds[w][(16 + lhi * 4 + i) * 72 + sf * 16 + l16] = f2bf_hw(p);
      }
    if (actA) {
      bool maskA = (tt == ntA - 1);
#pragma unroll
      for (int sf = 0; sf < 4; ++sf)
#pragma unroll
        for (int i = 0; i < 4; ++i) {
          float p = exp2f(saccA[sf][i] - 16.0f);
          if (maskA) {
            int key = kv0 + sf * 16 + l16;
            int qr = rowA + lhi * 4 + i;
            if (key > qr) p = 0.f;
          }
          Plds[w][(lhi * 4 + i) * 72 + sf * 16 + l16] = f2bf_hw(p);
        }
    }
    // ---- PV (+ denominator via ones column)
    short8 apB[2];
#pragma unroll
    for (int kc = 0; kc < 2; ++kc)
      apB[kc] = *(const short8*)(&Plds[w][(16 + l16) * 72 + kc * 32 + lhi * 8]);
#pragma unroll
    for (int kc = 0; kc < 2; ++kc)
      acc1B = __builtin_amdgcn_mfma_f32_16x16x32_bf16(apB[kc], ones, acc1B, 0, 0, 0);
#pragma unroll
    for (int d = 0; d < 4; ++d)
#pragma unroll
      for (int kc = 0; kc < 2; ++kc)
        oaccB[d] = __builtin_amdgcn_mfma_f32_16x16x32_bf16(
            apB[kc], bv[d][kc], oaccB[d], 0, 0, 0);
    if (actA) {
      short8 apA[2];
#pragma unroll
      for (int kc = 0; kc < 2; ++kc)
        apA[kc] = *(const short8*)(&Plds[w][l16 * 72 + kc * 32 + lhi * 8]);
#pragma unroll
      for (int kc = 0; kc < 2; ++kc)
        acc1A = __builtin_amdgcn_mfma_f32_16x16x32_bf16(apA[kc], ones, acc1A, 0, 0, 0);
#pragma unroll
      for (int d = 0; d < 4; ++d)
#pragma unroll
        for (int kc = 0; kc < 2; ++kc)
          oaccA[d] = __builtin_amdgcn_mfma_f32_16x16x32_bf16(
              apA[kc], bv[d][kc], oaccA[d], 0, 0, 0);
    }
    // prefetch next V tile
    if (tt + 1 < ntB) {
      int nk = kv0 + 64;
#pragma unroll
      for (int d = 0; d < 4; ++d)
#pragma unroll
        for (int kc = 0; kc < 2; ++kc)
          bv[d][kc] = *(const short8*)(Vb + (size_t)(d * 16 + l16) * SS + nk +
                                       kc * 32 + lhi * 8);
    }
  }

  // epilogue: broadcast denominators (col 0) and write both fragments
#pragma unroll
  for (int i = 0; i < 4; ++i) {
    float lA = __shfl(acc1A[i], lane & 48);
    float lB = __shfl(acc1B[i], lane & 48);
    float invA = 1.0f / lA, invB = 1.0f / lB;
    int sA = rowA + lhi * 4 + i;
    int sB = rowB + lhi * 4 + i;
#pragma unroll
    for (int d = 0; d < 4; ++d) {
      O[(size_t)(b * SS + sA) * DD + h * DKK + d * 16 + l16] =
          f2bf(oaccA[d][i] * invA);
      O[(size_t)(b * SS + sB) * DD + h * DKK + d * 16 + l16] =
          f2bf(oaccB[d][i] * invB);
    }
  }
}

// ---------------------------------------------------------------- launch
extern "C" void kernel_launch(void* const* d_in, const int* in_sizes, int n_in,
                              void* d_out, int out_size, void* d_ws, size_t ws_size,
                              hipStream_t stream) {
  const float* x  = (const float*)d_in[0];
  const float* WQ = (const float*)d_in[1];
  const float* WK = (const float*)d_in[2];
  const float* WV = (const float*)d_in[3];
  const float* WO = (const float*)d_in[4];
  float* out = (float*)d_out;

  const size_t NX = (size_t)BB * SS * DD;   // 8.39M
  const size_t NW = (size_t)DD * DD;        // 1.05M

  unsigned short* xb   = (unsigned short*)d_ws;
  unsigned short* wcat = xb + NX;           // [wq|wk|wv|wo] contiguous
  unsigned short* wo   = wcat + 3 * NW;
  unsigned short* Qh   = wcat + 4 * NW;
  unsigned short* Kh   = Qh + NX;
  unsigned short* Vt   = Kh + NX;
  unsigned short* attn = Vt + NX;

  convert_f32_bf16<<<(int)(NX / 4 / 256), 256, 0, stream>>>(x, xb, (int)(NX / 4));
  convert_w4<<<dim3((unsigned)(NW / 4 / 256), 4), 256, 0, stream>>>(
      WQ, WK, WV, WO, wcat, (int)(NW / 4));

  gemm_qkv<<<64 * 24, 256, 0, stream>>>(xb, wcat, Qh, Kh, Vt);

  attn_kernel<<<64 * 16, 256, 0, stream>>>(Qh, Kh, Vt, attn);

  gemm_wo<<<64 * 8, 256, 0, stream>>>(attn, wo, out, DD, DD);
}